// Round 8
// baseline (125.226 us; speedup 1.0000x reference)
//
#include <hip/hip_runtime.h>
#include <hip/hip_bf16.h>
#include <stdint.h>

#define BDIM 256

typedef __attribute__((ext_vector_type(8))) short short8;
typedef __attribute__((ext_vector_type(4))) float f32x4;
typedef __attribute__((ext_vector_type(4))) unsigned int u32x4;

__device__ __forceinline__ unsigned short f2bf(float f) {
  union { float f; unsigned u; } v; v.f = f;
  unsigned r = v.u + 0x7fffu + ((v.u >> 16) & 1u);  // round-to-nearest-even
  return (unsigned short)(r >> 16);
}
__device__ __forceinline__ float bf2f(unsigned short u) {
  union { unsigned u; float f; } v; v.u = ((unsigned)u) << 16;
  return v.f;
}

// ---- weight conversion: W1 [1024,676] -> bf16 [1024,704] zero-padded K ----
__global__ __launch_bounds__(BDIM) void cast_pad_w1(const float* __restrict__ w,
                                                    unsigned short* __restrict__ o) {
  int idx = blockIdx.x * BDIM + threadIdx.x;
  if (idx >= 1024 * 704) return;
  int n = idx / 704, k = idx - n * 704;
  float v = (k < 676) ? w[n * 676 + k] : 0.f;
  o[idx] = f2bf(v);
}

__global__ __launch_bounds__(BDIM) void cast_plain(const float* __restrict__ w,
                                                   unsigned short* __restrict__ o, int count) {
  int idx = blockIdx.x * BDIM + threadIdx.x;
  if (idx < count) o[idx] = f2bf(w[idx]);
}

// ---- conv 3x3 VALID, 28x28 -> 26x26, f32 compute, bf16 out padded 676->704 ----
__global__ __launch_bounds__(BDIM) void conv3x3(const float* __restrict__ x,
                                                const float* __restrict__ cw,
                                                unsigned short* __restrict__ h0) {
  __shared__ float xs[784];
  __shared__ float w[9];
  int m = blockIdx.x;
  const float* xr = x + (size_t)m * 784;
  if (threadIdx.x < 9) w[threadIdx.x] = cw[threadIdx.x];
  for (int i = threadIdx.x; i < 784; i += BDIM) xs[i] = xr[i];
  __syncthreads();
  unsigned short* hr = h0 + (size_t)m * 704;
  for (int p = threadIdx.x; p < 704; p += BDIM) {
    float v = 0.f;
    if (p < 676) {
      int r = p / 26, c = p - r * 26;
      const float* xp = &xs[r * 28 + c];
      v = xp[0]  * w[0] + xp[1]  * w[1] + xp[2]  * w[2]
        + xp[28] * w[3] + xp[29] * w[4] + xp[30] * w[5]
        + xp[56] * w[6] + xp[57] * w[7] + xp[58] * w[8];
    }
    hr[p] = f2bf(v);
  }
}

// ---- fine-phase GEMM, REG-STAGED (T14 generalized) ----
// C = act(A * Wt^T + bias) -> bf16. A [M,K] bf16, Wt [N,K] bf16.
// r7 skeleton (phases, barriers, swizzle invariant, epilogue, XCD map)
// unchanged; ONE variable changed: staging path. global_load_lds replaced by
// plain global_load_dwordx4 -> VGPR -> swizzled ds_write_b128.
// Rationale (r4-r7 invariance): per-tile time tracked staged BYTES at
// ~9 B/cyc/CU across 3 sync structures + 2 mappings -> gload_lds completion
// is concurrency-limited at L2-cold latency. Plain loads give 64KB/CU in
// flight (8 waves x 8 x 1KB) -> latency-hiding by Little's law.
// Loads for tile t+1 issue at ph0 of tile t (pinned by sched_barrier(0)
// fences); regs consumed by ds_write at the last phase (compiler inserts the
// vmcnt wait); explicit lgkmcnt(0) before the end barrier for visibility.
template <int BM, int BN, int WGM, bool RELU>
__global__ __launch_bounds__(512, 2) void gemm_bt4(const unsigned short* __restrict__ A,
                                                   const unsigned short* __restrict__ Wt,
                                                   const float* __restrict__ bias,
                                                   unsigned short* __restrict__ Cb,
                                                   int M, int N, int K) {
  constexpr int WGN = 8 / WGM;
  constexpr int FM = BM / WGM / 16;   // M-fragments per wave
  constexpr int FN = BN / WGN / 16;   // N-fragments per wave
  constexpr int RA = BM / 64;         // 64-row staging rounds (A), 1 load/thread each
  constexpr int RB = BN / 64;         // same for B
  constexpr int NPH = (FM == 8) ? 4 : 2;  // phases per K-tile
  constexpr int MPG = FM / NPH;       // m-fragments per phase
  __shared__ unsigned short lds[(size_t)(BM + BN) * 128];
  unsigned short* const Asb = lds;                 // [2][BM*64]
  unsigned short* const Bsb = lds + 2 * BM * 64;   // [2][BN*64]

  const int tid = threadIdx.x;
  const int lane = tid & 63;
  const int wid = tid >> 6;

  // ---- chunked XCD mapping (kept from r7; neutral but theoretically right) --
  const int nbm = M / BM, nbc = N / BN;
  int brow, bcol;
  if (nbm * nbc == 256) {
    const int nid = ((int)blockIdx.x % 8) * 32 + ((int)blockIdx.x / 8);
    const int bpr = 32 / nbc;                    // brow-blocks per chunk
    brow = ((nid >> 5) * bpr + (nid & 31) / nbc) * BM;
    bcol = (nid % nbc) * BN;
  } else {                                       // fallback: plain mapping
    brow = ((int)blockIdx.x % nbm) * BM;
    bcol = ((int)blockIdx.x / nbm) * BN;
  }

  // staging: round r covers tile rows [r*64, r*64+64). Thread t -> row r*64+t/8,
  // 16B at col-slot (t&7) -- LINEAR global source (8 lanes cover one 128B line).
  // ds_write goes to slot (t&7)^(row&7): LDS[row][q] = tile[row][q ^ (row&7)]
  // (same involution as r4-r7; read side unchanged).
  const int srow = tid >> 3;
  const unsigned short* gA = A + (size_t)(brow + srow) * K + (tid & 7) * 8;
  const unsigned short* gB = Wt + (size_t)(bcol + srow) * K + (tid & 7) * 8;
  const int wslot = ((tid & 7) ^ (srow & 7)) << 3;   // element offset in row

  u32x4 avr[RA], bvr[RB];   // in-flight staging registers (static indexing only)

#define LOADT(kt)                                                             \
  do { _Pragma("unroll")                                                      \
    for (int r = 0; r < RA; ++r)                                              \
      avr[r] = *(const u32x4*)(gA + (size_t)r * 64 * K + (size_t)(kt) * 64);  \
    _Pragma("unroll")                                                         \
    for (int r = 0; r < RB; ++r)                                              \
      bvr[r] = *(const u32x4*)(gB + (size_t)r * 64 * K + (size_t)(kt) * 64);  \
  } while (0)
#define WRITET(buf)                                                           \
  do { _Pragma("unroll")                                                      \
    for (int r = 0; r < RA; ++r)                                              \
      *(u32x4*)(Asb + (buf) * BM * 64 + (r * 64 + srow) * 64 + wslot) = avr[r]; \
    _Pragma("unroll")                                                         \
    for (int r = 0; r < RB; ++r)                                              \
      *(u32x4*)(Bsb + (buf) * BN * 64 + (r * 64 + srow) * 64 + wslot) = bvr[r]; \
  } while (0)

  f32x4 acc[FM][FN] = {};
  const int fr = lane & 15;            // row within 16x16 fragment
  const int h = lane >> 4;             // k-subgroup 0..3 (8 elems each)
  const int fx = fr & 7;               // read-side swizzle XOR (= row&7)
  const int abase = (wid / WGN) * (FM * 16);
  const int bbase = (wid % WGN) * (FN * 16);

  const int nk = K >> 6;               // >= 8 for all layers here
  // prologue: stage tiles 0 and 1 (serial; ~2 round-trips, amortized over nk)
  LOADT(0);
  WRITET(0);                           // compiler inserts vmcnt waits on reg use
  LOADT(1);
  WRITET(1);
  asm volatile("s_waitcnt lgkmcnt(0)" ::: "memory");
  __builtin_amdgcn_sched_barrier(0);
  __builtin_amdgcn_s_barrier();
  __builtin_amdgcn_sched_barrier(0);

  for (int kt = 0; kt < nk; ++kt) {
    const int cur = kt & 1;
    const unsigned short* As0 = Asb + cur * BM * 64;
    const unsigned short* Bs0 = Bsb + cur * BN * 64;
    short8 bf[FN][2];                  // B frags live across all phases of tile
#pragma unroll
    for (int ph = 0; ph < NPH; ++ph) {
      // ---- ds_read issue (async; compiler inserts lgkm waits at MFMA use) --
      if (ph == 0) {
#pragma unroll
        for (int n = 0; n < FN; ++n)
#pragma unroll
          for (int s = 0; s < 2; ++s)
            bf[n][s] = *(const short8*)&Bs0[(bbase + n * 16 + fr) * 64 + ((((s << 2) + h) ^ fx) << 3)];
      }
      short8 af[MPG][2];
#pragma unroll
      for (int mm = 0; mm < MPG; ++mm)
#pragma unroll
        for (int s = 0; s < 2; ++s)
          af[mm][s] = *(const short8*)&As0[(abase + (ph * MPG + mm) * 16 + fr) * 64 + ((((s << 2) + h) ^ fx) << 3)];
      // ---- issue next tile's global loads early (hide full latency) --------
      if (ph == 0 && kt + 1 < nk) LOADT(kt + 1);
      __builtin_amdgcn_sched_barrier(0);
      __builtin_amdgcn_s_barrier();          // mid: phase lockstep
      __builtin_amdgcn_sched_barrier(0);
      __builtin_amdgcn_s_setprio(1);         // T5
#pragma unroll
      for (int s = 0; s < 2; ++s)            // s outer: independent MFMAs between dep pairs
#pragma unroll
        for (int mm = 0; mm < MPG; ++mm)
#pragma unroll
          for (int n = 0; n < FN; ++n)
            acc[ph * MPG + mm][n] =
                __builtin_amdgcn_mfma_f32_16x16x32_bf16(af[mm][s], bf[n][s], acc[ph * MPG + mm][n], 0, 0, 0);
      __builtin_amdgcn_s_setprio(0);
      __builtin_amdgcn_sched_barrier(0);
      if (ph == NPH - 1) {                   // once per tile: commit t+1 to LDS
        if (kt + 1 < nk) {
          WRITET(cur ^ 1);                   // buf cur^1 is dead (held t-1)
          asm volatile("s_waitcnt lgkmcnt(0)" ::: "memory");
          __builtin_amdgcn_sched_barrier(0);
        }
      }
      __builtin_amdgcn_s_barrier();          // end-of-phase / tile handoff
      __builtin_amdgcn_sched_barrier(0);
    }
  }
#undef LOADT
#undef WRITET

  // ---- epilogue: frags -> LDS scratch (swizzled) -> coalesced 16B stores ----
  unsigned short* const scr = lds;  // BM*BN <= (BM+BN)*128 for all configs here
  const int lrow0 = abase + (h << 2);  // local row of j=0
  const int lcol0 = bbase + fr;
#pragma unroll
  for (int n = 0; n < FN; ++n) {
    const int col = lcol0 + n * 16;
    const float bv = bias[bcol + col];
#pragma unroll
    for (int m = 0; m < FM; ++m) {
#pragma unroll
      for (int j = 0; j < 4; ++j) {
        const int row = lrow0 + m * 16 + j;
        float v = acc[m][n][j] + bv;
        if (RELU) v = v > 0.f ? v : 0.f;
        scr[(row * BN + col) ^ ((row & 12) << 2)] = f2bf(v);
      }
    }
  }
  __syncthreads();
  constexpr int CPR = BN / 8;        // 16B chunks per row
  constexpr int TOT = BM * CPR;
#pragma unroll 2
  for (int i = tid; i < TOT; i += 512) {
    const int row = i / CPR, c = i % CPR;
    const int cs = c ^ ((row & 12) >> 1);     // same XOR at chunk granularity
    short8 vv = *(const short8*)&scr[row * BN + cs * 8];
    *(short8*)(Cb + (size_t)(brow + row) * N + bcol + c * 8) = vv;
  }
}

// ---- final layer: out[m,n] = sum_k h3[m,k]*W4[n,k] + b4[n], N=10, K=256, f32 out ----
__global__ __launch_bounds__(BDIM) void fc10(const unsigned short* __restrict__ h3,
                                             const float* __restrict__ W4,
                                             const float* __restrict__ b4,
                                             float* __restrict__ out) {
  int lane = threadIdx.x & 63;
  int wid = threadIdx.x >> 6;
  int m = blockIdx.x * 4 + wid;
  const unsigned short* hr = h3 + (size_t)m * 256 + lane * 4;
  uint64_t hv = *(const uint64_t*)hr;
  float e0 = bf2f((unsigned short)hv), e1 = bf2f((unsigned short)(hv >> 16));
  float e2 = bf2f((unsigned short)(hv >> 32)), e3 = bf2f((unsigned short)(hv >> 48));
#pragma unroll
  for (int n = 0; n < 10; ++n) {
    const float4 wv = *(const float4*)(W4 + n * 256 + lane * 4);
    float s = e0 * wv.x + e1 * wv.y + e2 * wv.z + e3 * wv.w;
#pragma unroll
    for (int off = 32; off > 0; off >>= 1) s += __shfl_xor(s, off);
    if (lane == n) out[(size_t)m * 10 + n] = s + b4[n];
  }
}

extern "C" void kernel_launch(void* const* d_in, const int* in_sizes, int n_in,
                              void* d_out, int out_size, void* d_ws, size_t ws_size,
                              hipStream_t stream) {
  const float* x  = (const float*)d_in[0];
  const float* cw = (const float*)d_in[1];
  const float* W1 = (const float*)d_in[2];
  const float* b1 = (const float*)d_in[3];
  const float* W2 = (const float*)d_in[4];
  const float* b2 = (const float*)d_in[5];
  const float* W3 = (const float*)d_in[6];
  const float* b3 = (const float*)d_in[7];
  const float* W4 = (const float*)d_in[8];
  const float* b4 = (const float*)d_in[9];
  float* out = (float*)d_out;

  char* ws = (char*)d_ws;
  // h0 [16384,704] bf16 (23,068,672 B) — region reused for h2 [16384,512]
  // h1 [16384,1024] bf16 (33,554,432 B) — region reused for h3 [16384,256]
  unsigned short* h0  = (unsigned short*)(ws);
  unsigned short* h1  = (unsigned short*)(ws + 23068672);
  unsigned short* W1b = (unsigned short*)(ws + 23068672 + 33554432);
  unsigned short* W2b = W1b + 1024 * 704;
  unsigned short* W3b = W2b + 512 * 1024;
  unsigned short* h2  = h0;
  unsigned short* h3  = h1;

  cast_pad_w1<<<2816, BDIM, 0, stream>>>(W1, W1b);
  cast_plain<<<2048, BDIM, 0, stream>>>(W2, W2b, 512 * 1024);
  cast_plain<<<512, BDIM, 0, stream>>>(W3, W3b, 256 * 512);
  conv3x3<<<16384, BDIM, 0, stream>>>(x, cw, h0);

  // GEMM1: M=16384 N=1024 K=704 (11 K-tiles). 4 phases x 16 MFMA. grid 256.
  gemm_bt4<256, 256, 2, true><<<(16384 / 256) * (1024 / 256), 512, 0, stream>>>(
      h0, W1b, b1, h1, 16384, 1024, 704);
  // GEMM2: M=16384 N=512 K=1024 (16 K-tiles). 2 phases x 16 MFMA. grid 256.
  gemm_bt4<256, 128, 4, true><<<(16384 / 256) * (512 / 128), 512, 0, stream>>>(
      h1, W2b, b2, h2, 16384, 512, 1024);
  // GEMM3: M=16384 N=256 K=512 (8 K-tiles). 2 phases x 8 MFMA. grid 256.
  gemm_bt4<128, 128, 4, true><<<(16384 / 128) * (256 / 128), 512, 0, stream>>>(
      h2, W3b, b3, h3, 16384, 256, 512);
  fc10<<<16384 / 4, BDIM, 0, stream>>>(h3, W4, b4, out);
}

// Round 9
// 123.495 us; speedup vs baseline: 1.0140x; 1.0140x over previous
//
#include <hip/hip_runtime.h>
#include <hip/hip_bf16.h>
#include <stdint.h>

#define BDIM 256

typedef __attribute__((ext_vector_type(8))) short short8;
typedef __attribute__((ext_vector_type(4))) float f32x4;

#define AS1 __attribute__((address_space(1)))
#define AS3 __attribute__((address_space(3)))
// async global->LDS DMA, 16B/lane; LDS dest must be wave-uniform base + lane*16 (m104/m108)
#define GLL16(g, s) __builtin_amdgcn_global_load_lds((AS1 const void*)(g), (AS3 void*)(s), 16, 0, 0)

__device__ __forceinline__ unsigned short f2bf(float f) {
  union { float f; unsigned u; } v; v.f = f;
  unsigned r = v.u + 0x7fffu + ((v.u >> 16) & 1u);  // round-to-nearest-even
  return (unsigned short)(r >> 16);
}
__device__ __forceinline__ float bf2f(unsigned short u) {
  union { unsigned u; float f; } v; v.u = ((unsigned)u) << 16;
  return v.f;
}

// ---- weight conversion: W1 [1024,676] -> bf16 [1024,704] zero-padded K ----
__global__ __launch_bounds__(BDIM) void cast_pad_w1(const float* __restrict__ w,
                                                    unsigned short* __restrict__ o) {
  int idx = blockIdx.x * BDIM + threadIdx.x;
  if (idx >= 1024 * 704) return;
  int n = idx / 704, k = idx - n * 704;
  float v = (k < 676) ? w[n * 676 + k] : 0.f;
  o[idx] = f2bf(v);
}

__global__ __launch_bounds__(BDIM) void cast_plain(const float* __restrict__ w,
                                                   unsigned short* __restrict__ o, int count) {
  int idx = blockIdx.x * BDIM + threadIdx.x;
  if (idx < count) o[idx] = f2bf(w[idx]);
}

// ---- conv 3x3 VALID, 28x28 -> 26x26, f32 compute, bf16 out padded 676->704 ----
__global__ __launch_bounds__(BDIM) void conv3x3(const float* __restrict__ x,
                                                const float* __restrict__ cw,
                                                unsigned short* __restrict__ h0) {
  __shared__ float xs[784];
  __shared__ float w[9];
  int m = blockIdx.x;
  const float* xr = x + (size_t)m * 784;
  if (threadIdx.x < 9) w[threadIdx.x] = cw[threadIdx.x];
  for (int i = threadIdx.x; i < 784; i += BDIM) xs[i] = xr[i];
  __syncthreads();
  unsigned short* hr = h0 + (size_t)m * 704;
  for (int p = threadIdx.x; p < 704; p += BDIM) {
    float v = 0.f;
    if (p < 676) {
      int r = p / 26, c = p - r * 26;
      const float* xp = &xs[r * 28 + c];
      v = xp[0]  * w[0] + xp[1]  * w[1] + xp[2]  * w[2]
        + xp[28] * w[3] + xp[29] * w[4] + xp[30] * w[5]
        + xp[56] * w[6] + xp[57] * w[7] + xp[58] * w[8];
    }
    hr[p] = f2bf(v);
  }
}

// ---- multi-chain GEMM: C[m,n] = act(sum_k A[m,k]*Wt[n,k] + bias[n]) -> bf16 ----
// A [M,K] bf16, Wt [N,K] bf16. SMALL tiles, BK=32, 256 threads = 4 waves,
// LDS <= 32 KB -> 4-5 blocks/CU resident ("chains"). Theory (r4-r8 invariance
// + m102/m97 shape curve): per-block staging chain sustains only ~7 B/cyc at
// L3-class latency regardless of sync structure; per-CU throughput = rate x
// resident chains. 1-block/CU 256^2 tiles (r4-r8) were chain-starved; this
// kernel restores m97's 4-chain overlap (m114 mechanism) and keeps r4's two
// measured wins:
//  * XOR swizzle (slot^=row&3 at BK=32), rule-21 both-sides form: linear
//    gload_lds dest + pre-swizzled global source + same XOR on ds_read
//    -> 0 bank conflicts (r4-verified at the BK=64 variant).
//  * LDS-transpose epilogue -> coalesced 16B stores (WRITE = ideal, r4).
// Sync = simple drain loop (STAGE next -> read+MFMA cur -> __syncthreads);
// the drain is covered by OTHER resident blocks' compute.
template <int BM, int BN, int WGM, bool RELU>
__global__ __launch_bounds__(BDIM, 4) void gemm_bt5(const unsigned short* __restrict__ A,
                                                    const unsigned short* __restrict__ Wt,
                                                    const float* __restrict__ bias,
                                                    unsigned short* __restrict__ Cb,
                                                    int M, int N, int K) {
  constexpr int WGN = 4 / WGM;
  constexpr int FM = BM / WGM / 16;   // M-fragments per wave
  constexpr int FN = BN / WGN / 16;   // N-fragments per wave
  constexpr int RA = BM / 64;         // 64-row staging rounds for A (1 GLL16/thread each)
  constexpr int RB = BN / 64;
  __shared__ unsigned short lds[2 * (BM + BN) * 32];
  unsigned short* const Asb = lds;                 // [2][BM*32]
  unsigned short* const Bsb = lds + 2 * BM * 32;   // [2][BN*32]

  const int tid = threadIdx.x;
  const int lane = tid & 63;
  const int wid = tid >> 6;

  // ---- chunked XCD mapping: XCD x gets grid/8 consecutive tiles
  // (bcol fastest) -> same-XCD blocks share A-slabs and the whole B panel.
  const int nbm = M / BM, nbc = N / BN;
  const int grid = nbm * nbc;          // always multiple of 8 here
  const int cpx = grid >> 3;
  const int nid = ((int)blockIdx.x & 7) * cpx + ((int)blockIdx.x >> 3);
  const int brow = (nid / nbc) * BM;
  const int bcol = (nid % nbc) * BN;

  // staging: round r covers tile rows [r*64, r*64+64). Thread t -> row r*64+t/4,
  // 16B slot t&3. LDS dest linear (t*16B). Source slot PRE-SWIZZLED:
  // slot ^ (row&3), so LDS[row][q] = tile[row][q ^ (row&3)] (involution).
  const int srow = tid >> 2;
  const int sslot = (tid & 3) ^ (srow & 3);
  const unsigned short* gA = A + (size_t)(brow + srow) * K + sslot * 8;
  const unsigned short* gB = Wt + (size_t)(bcol + srow) * K + sslot * 8;
  const int sdst = tid * 8;  // elements

#define STAGE(buf, kt)                                                        \
  do {                                                                        \
    _Pragma("unroll")                                                         \
    for (int r = 0; r < RA; ++r)                                              \
      GLL16(gA + (size_t)r * 64 * K + (size_t)(kt) * 32,                      \
            Asb + (buf) * BM * 32 + r * 2048 + sdst);                         \
    _Pragma("unroll")                                                         \
    for (int r = 0; r < RB; ++r)                                              \
      GLL16(gB + (size_t)r * 64 * K + (size_t)(kt) * 32,                      \
            Bsb + (buf) * BN * 32 + r * 2048 + sdst);                         \
  } while (0)

  f32x4 acc[FM][FN] = {};
  const int fr = lane & 15;            // row within 16x16 fragment
  const int h = lane >> 4;             // k-subgroup 0..3 (8 elems each)
  const int fx = fr & 3;               // read-side swizzle XOR (= row&3)
  const int abase = (wid / WGN) * (FM * 16);
  const int bbase = (wid % WGN) * (FN * 16);
  const int slot = (h ^ fx) << 3;      // swizzled element offset within row

  const int nk = K >> 5;
  STAGE(0, 0);
  __syncthreads();
  int cur = 0;
  for (int kt = 0; kt < nk; ++kt) {
    if (kt + 1 < nk) STAGE(cur ^ 1, kt + 1);   // prefetch overlaps MFMA
    const unsigned short* As0 = Asb + cur * BM * 32;
    const unsigned short* Bs0 = Bsb + cur * BN * 32;
    short8 af[FM], bf[FN];
#pragma unroll
    for (int m = 0; m < FM; ++m)
      af[m] = *(const short8*)&As0[(abase + m * 16 + fr) * 32 + slot];
#pragma unroll
    for (int n = 0; n < FN; ++n)
      bf[n] = *(const short8*)&Bs0[(bbase + n * 16 + fr) * 32 + slot];
#pragma unroll
    for (int m = 0; m < FM; ++m)
#pragma unroll
      for (int n = 0; n < FN; ++n)
        acc[m][n] = __builtin_amdgcn_mfma_f32_16x16x32_bf16(af[m], bf[n], acc[m][n], 0, 0, 0);
    __syncthreads();                           // readers done + DMA drained
    cur ^= 1;
  }
#undef STAGE

  // ---- epilogue: frags -> LDS scratch (swizzled) -> coalesced 16B stores ----
  // scratch fits: BM*BN <= 2*(BM+BN)*32 for all configs used here.
  unsigned short* const scr = lds;
  const int lrow0 = abase + (h << 2);  // local row of j=0
  const int lcol0 = bbase + fr;
#pragma unroll
  for (int n = 0; n < FN; ++n) {
    const int col = lcol0 + n * 16;
    const float bv = bias[bcol + col];
#pragma unroll
    for (int m = 0; m < FM; ++m) {
#pragma unroll
      for (int j = 0; j < 4; ++j) {
        const int row = lrow0 + m * 16 + j;
        float v = acc[m][n][j] + bv;
        if (RELU) v = v > 0.f ? v : 0.f;
        scr[(row * BN + col) ^ ((row & 12) << 2)] = f2bf(v);
      }
    }
  }
  __syncthreads();
  constexpr int CPR = BN / 8;        // 16B chunks per row
  constexpr int TOT = BM * CPR;
#pragma unroll 2
  for (int i = tid; i < TOT; i += BDIM) {
    const int row = i / CPR, c = i % CPR;
    const int cs = c ^ ((row & 12) >> 1);     // same XOR at chunk granularity
    short8 vv = *(const short8*)&scr[row * BN + cs * 8];
    *(short8*)(Cb + (size_t)(brow + row) * N + bcol + c * 8) = vv;
  }
}

// ---- final layer: out[m,n] = sum_k h3[m,k]*W4[n,k] + b4[n], N=10, K=256, f32 out ----
__global__ __launch_bounds__(BDIM) void fc10(const unsigned short* __restrict__ h3,
                                             const float* __restrict__ W4,
                                             const float* __restrict__ b4,
                                             float* __restrict__ out) {
  int lane = threadIdx.x & 63;
  int wid = threadIdx.x >> 6;
  int m = blockIdx.x * 4 + wid;
  const unsigned short* hr = h3 + (size_t)m * 256 + lane * 4;
  uint64_t hv = *(const uint64_t*)hr;
  float e0 = bf2f((unsigned short)hv), e1 = bf2f((unsigned short)(hv >> 16));
  float e2 = bf2f((unsigned short)(hv >> 32)), e3 = bf2f((unsigned short)(hv >> 48));
#pragma unroll
  for (int n = 0; n < 10; ++n) {
    const float4 wv = *(const float4*)(W4 + n * 256 + lane * 4);
    float s = e0 * wv.x + e1 * wv.y + e2 * wv.z + e3 * wv.w;
#pragma unroll
    for (int off = 32; off > 0; off >>= 1) s += __shfl_xor(s, off);
    if (lane == n) out[(size_t)m * 10 + n] = s + b4[n];
  }
}

extern "C" void kernel_launch(void* const* d_in, const int* in_sizes, int n_in,
                              void* d_out, int out_size, void* d_ws, size_t ws_size,
                              hipStream_t stream) {
  const float* x  = (const float*)d_in[0];
  const float* cw = (const float*)d_in[1];
  const float* W1 = (const float*)d_in[2];
  const float* b1 = (const float*)d_in[3];
  const float* W2 = (const float*)d_in[4];
  const float* b2 = (const float*)d_in[5];
  const float* W3 = (const float*)d_in[6];
  const float* b3 = (const float*)d_in[7];
  const float* W4 = (const float*)d_in[8];
  const float* b4 = (const float*)d_in[9];
  float* out = (float*)d_out;

  char* ws = (char*)d_ws;
  // h0 [16384,704] bf16 (23,068,672 B) — region reused for h2 [16384,512]
  // h1 [16384,1024] bf16 (33,554,432 B) — region reused for h3 [16384,256]
  unsigned short* h0  = (unsigned short*)(ws);
  unsigned short* h1  = (unsigned short*)(ws + 23068672);
  unsigned short* W1b = (unsigned short*)(ws + 23068672 + 33554432);
  unsigned short* W2b = W1b + 1024 * 704;
  unsigned short* W3b = W2b + 512 * 1024;
  unsigned short* h2  = h0;
  unsigned short* h3  = h1;

  cast_pad_w1<<<2816, BDIM, 0, stream>>>(W1, W1b);
  cast_plain<<<2048, BDIM, 0, stream>>>(W2, W2b, 512 * 1024);
  cast_plain<<<512, BDIM, 0, stream>>>(W3, W3b, 256 * 512);
  conv3x3<<<16384, BDIM, 0, stream>>>(x, cw, h0);

  // GEMM1: M=16384 N=1024 K=704 (22 K-tiles of 32). 128x128, grid 128*8=1024
  // = 4 blocks/CU (LDS 32 KB). Per-wave 64x64 (FM=FN=4).
  gemm_bt5<128, 128, 2, true><<<(16384 / 128) * (1024 / 128), BDIM, 0, stream>>>(
      h0, W1b, b1, h1, 16384, 1024, 704);
  // GEMM2: M=16384 N=512 K=1024 (32 K-tiles). 64x128, grid 256*4=1024 = 4/CU
  // (LDS 24 KB). Per-wave 64x32 (FM=4, FN=2).
  gemm_bt5<64, 128, 1, true><<<(16384 / 64) * (512 / 128), BDIM, 0, stream>>>(
      h1, W2b, b2, h2, 16384, 512, 1024);
  // GEMM3: M=16384 N=256 K=512 (16 K-tiles). 64x64, grid 256*4=1024 = 4/CU
  // (LDS 16 KB). Per-wave 32x32 (FM=FN=2).
  gemm_bt5<64, 64, 2, true><<<(16384 / 64) * (256 / 64), BDIM, 0, stream>>>(
      h2, W3b, b3, h3, 16384, 256, 512);
  fc10<<<16384 / 4, BDIM, 0, stream>>>(h3, W4, b4, out);
}